// Round 11
// baseline (158.181 us; speedup 1.0000x reference)
//
#include <hip/hip_runtime.h>
#include <math.h>

#define NSEQ 2048
#define CDIM 768
#define NH   12
#define HD   64
#define NB   2

typedef unsigned short u16;
typedef __attribute__((ext_vector_type(8))) short bf16x8;   // 8 bf16 = 4 VGPRs
typedef __attribute__((ext_vector_type(4))) float f32x4;
typedef __attribute__((ext_vector_type(8))) float f32x8;
typedef __attribute__((ext_vector_type(4))) __bf16 bf16x4t;
typedef __attribute__((ext_vector_type(8))) __bf16 bf16x8t;

// fp32 -> bf16 round-to-nearest-even (scalar epilogue paths)
__device__ __forceinline__ u16 f2bf(float x) {
    unsigned int u = __float_as_uint(x);
    u += 0x7fffu + ((u >> 16) & 1u);
    return (u16)(u >> 16);
}

// pack 8 fp32 -> 8 bf16 via compiler-generated v_cvt_pk_bf16_f32
__device__ __forceinline__ uint4 pack8(float4 a, float4 b) {
    f32x8 v = {a.x, a.y, a.z, a.w, b.x, b.y, b.z, b.w};
    union { bf16x8t t; uint4 u; } o;
    o.t = __builtin_convertvector(v, bf16x8t);
    return o.u;
}

// raw v_exp_f32 (2^x); log2e pre-baked into Wq scale
__device__ __forceinline__ float fexp2(float x) {
#if __has_builtin(__builtin_amdgcn_exp2f)
    return __builtin_amdgcn_exp2f(x);
#else
    float r; asm("v_exp_f32 %0, %1" : "=v"(r) : "v"(x)); return r;
#endif
}

#define LSTR 72    // epilogue scratch stride (u16)
#define ESTR 136   // V-epilogue transpose tile stride (u16): 128+8
#define PSTR 72    // attn P-tile row stride (u16): 64 + 8 pad (bank spread)

// async global->LDS, 16B per lane, LDS dest = wave-uniform base + lane*16
#define GLD16(gp, lp) __builtin_amdgcn_global_load_lds( \
    (__attribute__((address_space(1))) void*)(const void*)(gp), \
    (__attribute__((address_space(3))) void*)(void*)(lp), 16, 0, 0)

// ---------------------------------------------------------------------------
// Kernel 0: one-shot fp32->bf16 conversion of X, Wqkv, Wproj (R14-proven).
// Wq rows scaled by 0.125 * log2(e) so softmax uses raw v_exp_f32.
// ---------------------------------------------------------------------------
__global__ __launch_bounds__(256)
void conv_kernel(const float* __restrict__ Xf, const float* __restrict__ Wqkv,
                 const float* __restrict__ Wproj, u16* __restrict__ Xb,
                 u16* __restrict__ Wqb, u16* __restrict__ Wpb)
{
    const int c = blockIdx.x * 256 + threadIdx.x;   // 0..688127
    const float* src; u16* dst; int lc; float scl = 1.0f;
    if (c < 393216)      { src = Xf;    dst = Xb;  lc = c; }
    else if (c < 614400) { src = Wqkv;  dst = Wqb; lc = c - 393216;
                           if (lc < 73728) scl = 0.18033688011112042f; }
    else                 { src = Wproj; dst = Wpb; lc = c - 614400; }
    float4 a = *(const float4*)&src[(size_t)lc * 8];
    float4 b = *(const float4*)&src[(size_t)lc * 8 + 4];
    a.x *= scl; a.y *= scl; a.z *= scl; a.w *= scl;
    b.x *= scl; b.y *= scl; b.z *= scl; b.w *= scl;
    *(uint4*)&dst[(size_t)lc * 8] = pack8(a, b);
}

// ---------------------------------------------------------------------------
// Kernel 1: qkv = Xb @ Wqkvb^T, pure bf16 MFMA (R13-proven, frozen).
// ---------------------------------------------------------------------------
#define QKV_STAGE(BUF, kt_) do {                                              \
    _Pragma("unroll")                                                         \
    for (int it = 0; it < 4; ++it) {                                          \
        int ch = tid + 256 * it; int rr = ch >> 3;                            \
        int sc = ((ch & 7) ^ (rr & 7)) << 3;                                  \
        GLD16(Xg + (size_t)(m0 + rr) * CDIM + (kt_) + sc, &S[BUF][ch * 8]);   \
    }                                                                         \
    _Pragma("unroll")                                                         \
    for (int it = 0; it < 2; ++it) {                                          \
        int ch = tid + 256 * it; int rr = ch >> 3;                            \
        int sc = ((ch & 7) ^ (rr & 7)) << 3;                                  \
        GLD16(Wg + (size_t)(n0 + rr) * CDIM + (kt_) + sc,                     \
              &S[BUF][8192 + ch * 8]);                                        \
    }                                                                         \
} while (0)

__global__ __launch_bounds__(256)
void qkv_mfma_kernel(const u16* __restrict__ Xg, const u16* __restrict__ Wg,
                     u16* __restrict__ Qb, u16* __restrict__ Kb,
                     u16* __restrict__ Vb)
{
    __shared__ __align__(16) u16 S[2][12288];   // [buf][A 128x64 | B 64x64]

    const int tid  = threadIdx.x;
    const int lane = tid & 63;
    const int wid  = tid >> 6;
    const int l15  = lane & 15;
    const int quad = lane >> 4;
    const int swz  = (l15 & 7) << 3;

    // n-major-within-XCD bijective swizzle (1152 = 8 XCD x 4 m x 36 n)
    const int f  = blockIdx.x;
    const int xc = f & 7;
    const int s  = f >> 3;                  // 0..143
    const int m0 = (xc * 4 + (s & 3)) * 128;
    const int n0 = (s >> 2) * 64;

    f32x4 acc[2][4];
#pragma unroll
    for (int mi = 0; mi < 2; ++mi)
#pragma unroll
        for (int ni = 0; ni < 4; ++ni)
            acc[mi][ni] = (f32x4){0.f, 0.f, 0.f, 0.f};

    QKV_STAGE(0, 0);
    __syncthreads();

    int cur = 0;
    for (int kt = 0; kt < CDIM; kt += 64) {
        if (kt + 64 < CDIM) QKV_STAGE(cur ^ 1, kt + 64);

#pragma unroll
        for (int k = 0; k < 2; ++k) {
            bf16x8 af[2];
#pragma unroll
            for (int mi = 0; mi < 2; ++mi)
                af[mi] = *(const bf16x8*)
                    &S[cur][(wid * 32 + mi * 16 + l15) * 64
                            + ((quad * 8 + 32 * k) ^ swz)];
#pragma unroll
            for (int ni = 0; ni < 4; ++ni) {
                bf16x8 bfr = *(const bf16x8*)
                    &S[cur][8192 + (ni * 16 + l15) * 64
                            + ((quad * 8 + 32 * k) ^ swz)];
#pragma unroll
                for (int mi = 0; mi < 2; ++mi)
                    acc[mi][ni] = __builtin_amdgcn_mfma_f32_16x16x32_bf16(
                        af[mi], bfr, acc[mi][ni], 0, 0, 0);
            }
        }
        __syncthreads();
        cur ^= 1;
    }

    const int bi      = m0 >> 11;
    const int tokbase = m0 & 2047;
    const int nbase   = tokbase + wid * 32;
    const int sel     = n0 / CDIM;           // 0=q,1=k,2=v
    const int h       = (n0 % CDIM) >> 6;
    u16* Sf = &S[0][0];

    if (sel == 2) {
        u16* Ew = Sf;                        // shared 64(d) x 128(tok) tile
#pragma unroll
        for (int ni = 0; ni < 4; ++ni)
#pragma unroll
            for (int mi = 0; mi < 2; ++mi)
#pragma unroll
                for (int r = 0; r < 4; ++r)
                    Ew[(ni * 16 + l15) * ESTR + wid * 32 + mi * 16 + quad * 4 + r]
                        = f2bf(acc[mi][ni][r]);
        __syncthreads();
        u16* dst = Vb + (size_t)(bi * NH + h) * HD * NSEQ;   // [64][2048]
#pragma unroll
        for (int it = 0; it < 4; ++it) {
            int idx = tid + 256 * it;          // 1024 chunks = 64 rows x 16
            int dd  = idx >> 4;
            int c8  = (idx & 15) << 3;
            *(uint4*)&dst[(size_t)dd * NSEQ + tokbase + c8] =
                *(const uint4*)&Ew[dd * ESTR + c8];
        }
    } else {
        u16* dst = ((sel == 0) ? Qb : Kb) + (size_t)(bi * NH + h) * NSEQ * HD;
        u16* Ew = Sf + wid * 32 * LSTR;        // wave-private 32x72 tile
#pragma unroll
        for (int ni = 0; ni < 4; ++ni) {
            int dd = ni * 16 + l15;
            float invf = expf(-0.14391156831212787f * (float)(dd & ~1));
#pragma unroll
            for (int mi = 0; mi < 2; ++mi) {
                f32x4 val = acc[mi][ni];
#pragma unroll
                for (int r = 0; r < 4; ++r) {
                    float e = val[r];
                    float p = __shfl_xor(e, 1);    // pair partner (col^1)
                    int n = nbase + mi * 16 + quad * 4 + r;
                    float sv, cv;
                    __sincosf((float)n * invf, &sv, &cv);
                    float o = (dd & 1) ? (e * cv + p * sv)
                                       : (e * cv - p * sv);
                    Ew[(mi * 16 + quad * 4 + r) * LSTR + dd] = f2bf(o);
                }
            }
        }
#pragma unroll
        for (int it = 0; it < 4; ++it) {
            int ch  = lane + 64 * it;          // 32 rows x 8 chunks
            int tr  = ch >> 3;
            int gc8 = (ch & 7) << 3;
            *(uint4*)&dst[(size_t)(nbase + tr) * HD + gc8] =
                *(const uint4*)&Ew[tr * LSTR + gc8];
        }
    }
}

// ---------------------------------------------------------------------------
// Kernel 2: flash attention, bf16 MFMA. R18: key-split at 16x16.
// Model (m134): attn was LDS-pipe-bound — 12 waves/CU x ~20 b128-equiv/iter
// x 12cyc ~= 2.9k cyc/iter, matching the observed 3.5k cyc/iter. Fix: 4
// waves = (q-half wq x KEY-half wk); each wave covers 32q x 32keys ->
// per-iter LDS reads drop 20 -> 12 b128-equiv (-40%), MFMA/exp counts
// unchanged, 12 waves/CU kept (R3's TLP lesson), 16x16 conflict-clean
// fragments kept (R16's 32x32 lesson). PV is single-K-step (32 keys = K).
// Key-half partials (O, lacc) add through retired Ks/Vs LDS — the combine
// mechanism R16 proved correct. Staging/swizzles/exp2/setprio unchanged.
// ---------------------------------------------------------------------------
#define STAGE_KV(BUF, kt_) do {                                               \
    GLD16(Kg + ((size_t)(((kt_) << 6) + r0) * HD + cs),                       \
          &Ks[BUF][wid * 512]);                                               \
    GLD16(Kg + ((size_t)(((kt_) << 6) + r0 + 32) * HD + cs),                  \
          &Ks[BUF][wid * 512 + 2048]);                                        \
    GLD16(Vg + ((size_t)r0 * NSEQ + ((kt_) << 6) + cs),                       \
          &Vs[BUF][wid * 512]);                                               \
    GLD16(Vg + ((size_t)(r0 + 32) * NSEQ + ((kt_) << 6) + cs),                \
          &Vs[BUF][wid * 512 + 2048]);                                        \
} while (0)

#define ATTN_STEP(kt_, CUR, NXT) do {                                         \
    if ((kt_) + 1 < NSEQ / 64) STAGE_KV(NXT, (kt_) + 1);                      \
    f32x4 sacc[2][2];                                                         \
    _Pragma("unroll")                                                         \
    for (int g = 0; g < 2; ++g)                                               \
        _Pragma("unroll")                                                     \
        for (int mt = 0; mt < 2; ++mt)                                        \
            sacc[g][mt] = (f32x4){0.f, 0.f, 0.f, 0.f};                        \
    __builtin_amdgcn_s_setprio(1);                                            \
    _Pragma("unroll")                                                         \
    for (int k = 0; k < 2; ++k) {                                             \
        _Pragma("unroll")                                                     \
        for (int mt = 0; mt < 2; ++mt) {                                      \
            bf16x8 ak = *(const bf16x8*)                                      \
                &Ks[CUR][(wk * 32 + mt * 16 + l15) * 64                       \
                         + ((quad * 8 + 32 * k) ^ swz)];                      \
            sacc[0][mt] = __builtin_amdgcn_mfma_f32_16x16x32_bf16(            \
                ak, aq[0][k], sacc[0][mt], 0, 0, 0);                          \
            sacc[1][mt] = __builtin_amdgcn_mfma_f32_16x16x32_bf16(            \
                ak, aq[1][k], sacc[1][mt], 0, 0, 0);                          \
        }                                                                     \
    }                                                                         \
    __builtin_amdgcn_s_setprio(0);                                            \
    _Pragma("unroll")                                                         \
    for (int g = 0; g < 2; ++g)                                               \
        _Pragma("unroll")                                                     \
        for (int mt = 0; mt < 2; ++mt) {                                      \
            f32x4 ev;                                                         \
            _Pragma("unroll")                                                 \
            for (int r = 0; r < 4; ++r) ev[r] = fexp2(sacc[g][mt][r]);        \
            bf16x4t pbk = __builtin_convertvector(ev, bf16x4t);               \
            *(bf16x4t*)&Pw[l15 * PSTR + g * 32                                \
                           + ((mt * 16 + quad * 4) ^ pswz)] = pbk;            \
        }                                                                     \
    __builtin_amdgcn_s_setprio(1);                                            \
    {                                                                         \
        bf16x8 ap0 = *(const bf16x8*)                                         \
            &Pw[l15 * PSTR + ((quad * 8) ^ pswz)];                            \
        bf16x8 ap1 = *(const bf16x8*)                                         \
            &Pw[l15 * PSTR + 32 + ((quad * 8) ^ pswz)];                       \
        lacc[0] = __builtin_amdgcn_mfma_f32_16x16x32_bf16(                    \
            ap0, vone, lacc[0], 0, 0, 0);                                     \
        lacc[1] = __builtin_amdgcn_mfma_f32_16x16x32_bf16(                    \
            ap1, vone, lacc[1], 0, 0, 0);                                     \
        _Pragma("unroll")                                                     \
        for (int t = 0; t < 4; ++t) {                                         \
            bf16x8 bv = *(const bf16x8*)                                      \
                &Vs[CUR][(t * 16 + l15) * 64                                  \
                         + ((wk * 32 + quad * 8) ^ swz)];                     \
            O[0][t] = __builtin_amdgcn_mfma_f32_16x16x32_bf16(                \
                ap0, bv, O[0][t], 0, 0, 0);                                   \
            O[1][t] = __builtin_amdgcn_mfma_f32_16x16x32_bf16(                \
                ap1, bv, O[1][t], 0, 0, 0);                                   \
        }                                                                     \
    }                                                                         \
    __builtin_amdgcn_s_setprio(0);                                            \
    __syncthreads();                                                          \
} while (0)

__global__ __launch_bounds__(256)
void attn_kernel(const u16* __restrict__ Qb, const u16* __restrict__ Kb,
                 const u16* __restrict__ Vt, u16* __restrict__ AO)
{
    __shared__ __align__(16) u16 Ks[2][64 * 64];    // 16KB; combine scratch wq=0
    __shared__ __align__(16) u16 Vs[2][64 * 64];    // 16KB; combine scratch wq=1
    __shared__ __align__(16) u16 Ps[4][16 * PSTR];  // 18KB wave-private P

    const int tid  = threadIdx.x;
    const int lane = tid & 63;
    const int wid  = tid >> 6;
    const int wq   = wid >> 1;         // q-half: rows wq*32..+31
    const int wk   = wid & 1;          // key-half of each 64-key tile
    const int l15  = lane & 15;
    const int quad = lane >> 4;
    const int swz  = (l15 & 7) << 3;   // XOR swizzle for K/V frag reads
    const int pswz = (l15 & 3) << 3;   // within-32 XOR for P ops

    // XCD swizzle: xcd = f&7 -> bh in {3*xcd .. 3*xcd+2}; 96 blocks/XCD.
    const int f  = blockIdx.x;
    const int i  = f >> 3;
    const int bh = (f & 7) * 3 + (i >> 5);   // 0..23
    const int qt = i & 31;                   // 0..31

    const u16* Qg = Qb + ((size_t)bh * NSEQ + qt * 64) * HD;
    const u16* Kg = Kb + (size_t)bh * NSEQ * HD;
    const u16* Vg = Vt + (size_t)bh * HD * NSEQ;   // [64][2048]

    const int r0 = tid >> 3;
    const int cs = ((tid & 7) ^ (r0 & 7)) << 3;    // inverse-swizzled src col

    // Q fragments (one-time global read): wave's q-rows wq*32 + g*16 + l15
    bf16x8 aq[2][2];
#pragma unroll
    for (int g = 0; g < 2; ++g)
#pragma unroll
        for (int k = 0; k < 2; ++k)
            aq[g][k] = *(const bf16x8*)
                &Qg[(wq * 32 + g * 16 + l15) * HD + quad * 8 + 32 * k];

    union { u16 s[8]; bf16x8 v; } oneu;
#pragma unroll
    for (int ii = 0; ii < 8; ++ii) oneu.s[ii] = 0x3f80;   // bf16 1.0
    const bf16x8 vone = oneu.v;

    f32x4 O[2][4];
#pragma unroll
    for (int g = 0; g < 2; ++g)
#pragma unroll
        for (int t = 0; t < 4; ++t) O[g][t] = (f32x4){0.f, 0.f, 0.f, 0.f};
    f32x4 lacc[2];
    lacc[0] = (f32x4){0.f, 0.f, 0.f, 0.f};
    lacc[1] = (f32x4){0.f, 0.f, 0.f, 0.f};

    u16* Pw = Ps[wid];

    STAGE_KV(0, 0);
    __syncthreads();

    for (int kt = 0; kt < NSEQ / 64; kt += 2) {
        ATTN_STEP(kt, 0, 1);
        ATTN_STEP(kt + 1, 1, 0);
    }

    // Cross-wave key-half combine (fixed-max softmax: partials just add).
    // Scratch: O -> slots [0,512), lacc -> slots [512,640) of f32x4 (10KB).
    f32x4* CB = (wq == 0) ? (f32x4*)&Ks[0][0] : (f32x4*)&Vs[0][0];
    if (wk == 1) {
#pragma unroll
        for (int g = 0; g < 2; ++g) {
#pragma unroll
            for (int t = 0; t < 4; ++t)
                CB[(g * 4 + t) * 64 + lane] = O[g][t];
            CB[512 + g * 64 + lane] = lacc[g];
        }
    }
    __syncthreads();
    if (wk == 0) {
        const int b = bh / NH, h = bh % NH;
#pragma unroll
        for (int g = 0; g < 2; ++g) {
            f32x4 lsum = lacc[g] + CB[512 + g * 64 + lane];
            float inv4[4];
#pragma unroll
            for (int r = 0; r < 4; ++r) inv4[r] = 1.0f / lsum[r];
#pragma unroll
            for (int t = 0; t < 4; ++t) {
                f32x4 o = O[g][t] + CB[(g * 4 + t) * 64 + lane];
#pragma unroll
                for (int r = 0; r < 4; ++r) {
                    size_t orow = (size_t)b * NSEQ + qt * 64 + wq * 32
                                  + g * 16 + quad * 4 + r;
                    AO[orow * CDIM + h * HD + t * 16 + l15] =
                        f2bf(o[r] * inv4[r]);
                }
            }
        }
    }
}

// ---------------------------------------------------------------------------
// Kernel 3: out = AO @ Wprojb^T + bias, bf16 MFMA (R13-proven, frozen).
// ---------------------------------------------------------------------------
#define PROJ_STAGE(BUF, kt_) do {                                             \
    _Pragma("unroll")                                                         \
    for (int it = 0; it < 2; ++it) {                                          \
        int ch = tid + 256 * it; int rr = ch >> 3;                            \
        int sc = ((ch & 7) ^ (rr & 7)) << 3;                                  \
        GLD16(Ag + (size_t)(m0 + rr) * CDIM + (kt_) + sc, &S[BUF][ch * 8]);   \
        GLD16(Wg + (size_t)(n0 + rr) * CDIM + (kt_) + sc,                     \
              &S[BUF][4096 + ch * 8]);                                        \
    }                                                                         \
} while (0)

__global__ __launch_bounds__(256)
void proj_kernel(const u16* __restrict__ Ag, const u16* __restrict__ Wg,
                 const float* __restrict__ bias, float* __restrict__ out)
{
    __shared__ __align__(16) u16 S[2][8192];   // [buf][A 64x64 | B 64x64]
    const int tid  = threadIdx.x;
    const int lane = tid & 63;
    const int wid  = tid >> 6;
    const int l15  = lane & 15;
    const int quad = lane >> 4;
    const int swz  = (l15 & 7) << 3;
    const int wr = wid >> 1, wc = wid & 1;

    // XCD-pinned m-slices (768 = 8 XCD x 8 m x 12 n), n-major within XCD
    const int f  = blockIdx.x;
    const int xc = f & 7;
    const int s  = f >> 3;                  // 0..95
    const int m0 = (xc * 8 + (s & 7)) * 64;
    const int n0 = (s >> 3) * 64;

    f32x4 acc[2][2];
#pragma unroll
    for (int mi = 0; mi < 2; ++mi)
#pragma unroll
        for (int ni = 0; ni < 2; ++ni)
            acc[mi][ni] = (f32x4){0.f, 0.f, 0.f, 0.f};

    PROJ_STAGE(0, 0);
    __syncthreads();

    int cur = 0;
    for (int kt = 0; kt < CDIM; kt += 64) {
        if (kt + 64 < CDIM) PROJ_STAGE(cur ^ 1, kt + 64);

#pragma unroll
        for (int k = 0; k < 2; ++k) {
            bf16x8 af[2], bf[2];
#pragma unroll
            for (int mi = 0; mi < 2; ++mi)
                af[mi] = *(const bf16x8*)
                    &S[cur][(wr * 32 + mi * 16 + l15) * 64
                            + ((quad * 8 + 32 * k) ^ swz)];
#pragma unroll
            for (int ni = 0; ni < 2; ++ni)
                bf[ni] = *(const bf16x8*)
                    &S[cur][4096 + (wc * 32 + ni * 16 + l15) * 64
                            + ((quad * 8 + 32 * k) ^ swz)];
#pragma unroll
            for (int mi = 0; mi < 2; ++mi)
#pragma unroll
                for (int ni = 0; ni < 2; ++ni)
                    acc[mi][ni] = __builtin_amdgcn_mfma_f32_16x16x32_bf16(
                        af[mi], bf[ni], acc[mi][ni], 0, 0, 0);
        }
        __syncthreads();
        cur ^= 1;
    }

#pragma unroll
    for (int ni = 0; ni < 2; ++ni) {
        int col = n0 + wc * 32 + ni * 16 + l15;
        float bb = bias[col];
#pragma unroll
        for (int mi = 0; mi < 2; ++mi) {
            int rw = m0 + wr * 32 + mi * 16 + quad * 4;
#pragma unroll
            for (int r = 0; r < 4; ++r)
                out[(size_t)(rw + r) * CDIM + col] = acc[mi][ni][r] + bb;
        }
    }
}

// ---------------------------------------------------------------------------
extern "C" void kernel_launch(void* const* d_in, const int* in_sizes, int n_in,
                              void* d_out, int out_size, void* d_ws,
                              size_t ws_size, hipStream_t stream)
{
    const float* X     = (const float*)d_in[0];   // [2, 2048, 768]
    const float* Wqkv  = (const float*)d_in[1];   // [2304, 768]
    const float* Wproj = (const float*)d_in[2];   // [768, 768]
    const float* bias  = (const float*)d_in[3];   // [768]
    float* out = (float*)d_out;                   // [2, 2048, 768]

    const size_t per_buf = (size_t)NB * NH * NSEQ * HD;   // 3145728
    u16* Qb  = (u16*)d_ws;
    u16* Kb  = Qb + per_buf;
    u16* Vb  = Kb + per_buf;                      // [B,H,64,N]
    u16* XAO = Vb + per_buf;      // Xb (conv->qkv), then AO (attn->proj)
    u16* Wqb = XAO + per_buf;                     // [2304,768] bf16
    u16* Wpb = Wqb + (size_t)3 * CDIM * CDIM;     // [768,768] bf16

    conv_kernel<<<dim3(2688), 256, 0, stream>>>(X, Wqkv, Wproj, XAO, Wqb, Wpb);
    qkv_mfma_kernel<<<dim3(1152), 256, 0, stream>>>(XAO, Wqb, Qb, Kb, Vb);
    attn_kernel<<<dim3(768), 256, 0, stream>>>(Qb, Kb, Vb, XAO);
    proj_kernel<<<dim3(768), 256, 0, stream>>>(XAO, Wpb, bias, out);
}

// Round 12
// 144.819 us; speedup vs baseline: 1.0923x; 1.0923x over previous
//
#include <hip/hip_runtime.h>
#include <math.h>

#define NSEQ 2048
#define CDIM 768
#define NH   12
#define HD   64
#define NB   2

typedef unsigned short u16;
typedef __attribute__((ext_vector_type(8))) short bf16x8;   // 8 bf16 = 4 VGPRs
typedef __attribute__((ext_vector_type(4))) float f32x4;
typedef __attribute__((ext_vector_type(8))) float f32x8;
typedef __attribute__((ext_vector_type(4))) __bf16 bf16x4t;
typedef __attribute__((ext_vector_type(8))) __bf16 bf16x8t;

// fp32 -> bf16 round-to-nearest-even (scalar epilogue paths)
__device__ __forceinline__ u16 f2bf(float x) {
    unsigned int u = __float_as_uint(x);
    u += 0x7fffu + ((u >> 16) & 1u);
    return (u16)(u >> 16);
}

// pack 8 fp32 -> 8 bf16 via compiler-generated v_cvt_pk_bf16_f32
__device__ __forceinline__ uint4 pack8(float4 a, float4 b) {
    f32x8 v = {a.x, a.y, a.z, a.w, b.x, b.y, b.z, b.w};
    union { bf16x8t t; uint4 u; } o;
    o.t = __builtin_convertvector(v, bf16x8t);
    return o.u;
}

// raw v_exp_f32 (2^x); log2e pre-baked into Wq scale
__device__ __forceinline__ float fexp2(float x) {
#if __has_builtin(__builtin_amdgcn_exp2f)
    return __builtin_amdgcn_exp2f(x);
#else
    float r; asm("v_exp_f32 %0, %1" : "=v"(r) : "v"(x)); return r;
#endif
}

#define LSTR 72    // epilogue scratch stride (u16)
#define ESTR 136   // V-epilogue transpose tile stride (u16): 128+8

// async global->LDS, 16B per lane, LDS dest = wave-uniform base + lane*16
#define GLD16(gp, lp) __builtin_amdgcn_global_load_lds( \
    (__attribute__((address_space(1))) void*)(const void*)(gp), \
    (__attribute__((address_space(3))) void*)(void*)(lp), 16, 0, 0)

// ---------------------------------------------------------------------------
// Kernel 0: one-shot fp32->bf16 conversion of X, Wqkv, Wproj (R14-proven).
// Wq rows scaled by 0.125 * log2(e) so softmax uses raw v_exp_f32.
// ---------------------------------------------------------------------------
__global__ __launch_bounds__(256)
void conv_kernel(const float* __restrict__ Xf, const float* __restrict__ Wqkv,
                 const float* __restrict__ Wproj, u16* __restrict__ Xb,
                 u16* __restrict__ Wqb, u16* __restrict__ Wpb)
{
    const int c = blockIdx.x * 256 + threadIdx.x;   // 0..688127
    const float* src; u16* dst; int lc; float scl = 1.0f;
    if (c < 393216)      { src = Xf;    dst = Xb;  lc = c; }
    else if (c < 614400) { src = Wqkv;  dst = Wqb; lc = c - 393216;
                           if (lc < 73728) scl = 0.18033688011112042f; }
    else                 { src = Wproj; dst = Wpb; lc = c - 614400; }
    float4 a = *(const float4*)&src[(size_t)lc * 8];
    float4 b = *(const float4*)&src[(size_t)lc * 8 + 4];
    a.x *= scl; a.y *= scl; a.z *= scl; a.w *= scl;
    b.x *= scl; b.y *= scl; b.z *= scl; b.w *= scl;
    *(uint4*)&dst[(size_t)lc * 8] = pack8(a, b);
}

// ---------------------------------------------------------------------------
// Kernel 1: qkv = Xb @ Wqkvb^T, pure bf16 MFMA (R13-proven, frozen).
// ---------------------------------------------------------------------------
#define QKV_STAGE(BUF, kt_) do {                                              \
    _Pragma("unroll")                                                         \
    for (int it = 0; it < 4; ++it) {                                          \
        int ch = tid + 256 * it; int rr = ch >> 3;                            \
        int sc = ((ch & 7) ^ (rr & 7)) << 3;                                  \
        GLD16(Xg + (size_t)(m0 + rr) * CDIM + (kt_) + sc, &S[BUF][ch * 8]);   \
    }                                                                         \
    _Pragma("unroll")                                                         \
    for (int it = 0; it < 2; ++it) {                                          \
        int ch = tid + 256 * it; int rr = ch >> 3;                            \
        int sc = ((ch & 7) ^ (rr & 7)) << 3;                                  \
        GLD16(Wg + (size_t)(n0 + rr) * CDIM + (kt_) + sc,                     \
              &S[BUF][8192 + ch * 8]);                                        \
    }                                                                         \
} while (0)

__global__ __launch_bounds__(256)
void qkv_mfma_kernel(const u16* __restrict__ Xg, const u16* __restrict__ Wg,
                     u16* __restrict__ Qb, u16* __restrict__ Kb,
                     u16* __restrict__ Vb)
{
    __shared__ __align__(16) u16 S[2][12288];   // [buf][A 128x64 | B 64x64]

    const int tid  = threadIdx.x;
    const int lane = tid & 63;
    const int wid  = tid >> 6;
    const int l15  = lane & 15;
    const int quad = lane >> 4;
    const int swz  = (l15 & 7) << 3;

    // n-major-within-XCD bijective swizzle (1152 = 8 XCD x 4 m x 36 n)
    const int f  = blockIdx.x;
    const int xc = f & 7;
    const int s  = f >> 3;                  // 0..143
    const int m0 = (xc * 4 + (s & 3)) * 128;
    const int n0 = (s >> 2) * 64;

    f32x4 acc[2][4];
#pragma unroll
    for (int mi = 0; mi < 2; ++mi)
#pragma unroll
        for (int ni = 0; ni < 4; ++ni)
            acc[mi][ni] = (f32x4){0.f, 0.f, 0.f, 0.f};

    QKV_STAGE(0, 0);
    __syncthreads();

    int cur = 0;
    for (int kt = 0; kt < CDIM; kt += 64) {
        if (kt + 64 < CDIM) QKV_STAGE(cur ^ 1, kt + 64);

#pragma unroll
        for (int k = 0; k < 2; ++k) {
            bf16x8 af[2];
#pragma unroll
            for (int mi = 0; mi < 2; ++mi)
                af[mi] = *(const bf16x8*)
                    &S[cur][(wid * 32 + mi * 16 + l15) * 64
                            + ((quad * 8 + 32 * k) ^ swz)];
#pragma unroll
            for (int ni = 0; ni < 4; ++ni) {
                bf16x8 bfr = *(const bf16x8*)
                    &S[cur][8192 + (ni * 16 + l15) * 64
                            + ((quad * 8 + 32 * k) ^ swz)];
#pragma unroll
                for (int mi = 0; mi < 2; ++mi)
                    acc[mi][ni] = __builtin_amdgcn_mfma_f32_16x16x32_bf16(
                        af[mi], bfr, acc[mi][ni], 0, 0, 0);
            }
        }
        __syncthreads();
        cur ^= 1;
    }

    const int bi      = m0 >> 11;
    const int tokbase = m0 & 2047;
    const int nbase   = tokbase + wid * 32;
    const int sel     = n0 / CDIM;           // 0=q,1=k,2=v
    const int h       = (n0 % CDIM) >> 6;
    u16* Sf = &S[0][0];

    if (sel == 2) {
        u16* Ew = Sf;                        // shared 64(d) x 128(tok) tile
#pragma unroll
        for (int ni = 0; ni < 4; ++ni)
#pragma unroll
            for (int mi = 0; mi < 2; ++mi)
#pragma unroll
                for (int r = 0; r < 4; ++r)
                    Ew[(ni * 16 + l15) * ESTR + wid * 32 + mi * 16 + quad * 4 + r]
                        = f2bf(acc[mi][ni][r]);
        __syncthreads();
        u16* dst = Vb + (size_t)(bi * NH + h) * HD * NSEQ;   // [64][2048]
#pragma unroll
        for (int it = 0; it < 4; ++it) {
            int idx = tid + 256 * it;          // 1024 chunks = 64 rows x 16
            int dd  = idx >> 4;
            int c8  = (idx & 15) << 3;
            *(uint4*)&dst[(size_t)dd * NSEQ + tokbase + c8] =
                *(const uint4*)&Ew[dd * ESTR + c8];
        }
    } else {
        u16* dst = ((sel == 0) ? Qb : Kb) + (size_t)(bi * NH + h) * NSEQ * HD;
        u16* Ew = Sf + wid * 32 * LSTR;        // wave-private 32x72 tile
#pragma unroll
        for (int ni = 0; ni < 4; ++ni) {
            int dd = ni * 16 + l15;
            float invf = expf(-0.14391156831212787f * (float)(dd & ~1));
#pragma unroll
            for (int mi = 0; mi < 2; ++mi) {
                f32x4 val = acc[mi][ni];
#pragma unroll
                for (int r = 0; r < 4; ++r) {
                    float e = val[r];
                    float p = __shfl_xor(e, 1);    // pair partner (col^1)
                    int n = nbase + mi * 16 + quad * 4 + r;
                    float sv, cv;
                    __sincosf((float)n * invf, &sv, &cv);
                    float o = (dd & 1) ? (e * cv + p * sv)
                                       : (e * cv - p * sv);
                    Ew[(mi * 16 + quad * 4 + r) * LSTR + dd] = f2bf(o);
                }
            }
        }
#pragma unroll
        for (int it = 0; it < 4; ++it) {
            int ch  = lane + 64 * it;          // 32 rows x 8 chunks
            int tr  = ch >> 3;
            int gc8 = (ch & 7) << 3;
            *(uint4*)&dst[(size_t)(nbase + tr) * HD + gc8] =
                *(const uint4*)&Ew[tr * LSTR + gc8];
        }
    }
}

// ---------------------------------------------------------------------------
// Kernel 2: flash attention, bf16 MFMA — exact R14/R17-proven version
// (46.6 us). R19: permanent revert after R18's key-split regressed (56.1 us,
// conflicts 5.5x — reused XOR swizzle under a shifted column base is a new,
// unverified swizzle). Five structural variants (R2/R3/R15/R16/R18) all
// lost to this configuration, each for a distinct measured reason. 16x16
// S^T orientation, fixed-max softmax via raw v_exp_f32 (log2e in Wq),
// ones-MFMA denominator, gload_lds dbuf staging w/ source-XOR swizzle,
// ONE barrier/iter, setprio on MFMA clusters, XCD bh-pinning, 4 waves x
// 16 q-rows (12 waves/CU).
// ---------------------------------------------------------------------------
#define STAGE_KV(BUF, kt_) do {                                               \
    GLD16(Kg + ((size_t)(((kt_) << 6) + r0) * HD + cs),                       \
          &Ks[BUF][wid * 512]);                                               \
    GLD16(Kg + ((size_t)(((kt_) << 6) + r0 + 32) * HD + cs),                  \
          &Ks[BUF][wid * 512 + 2048]);                                        \
    GLD16(Vg + ((size_t)r0 * NSEQ + ((kt_) << 6) + cs),                       \
          &Vs[BUF][wid * 512]);                                               \
    GLD16(Vg + ((size_t)(r0 + 32) * NSEQ + ((kt_) << 6) + cs),                \
          &Vs[BUF][wid * 512 + 2048]);                                        \
} while (0)

#define ATTN_STEP(kt_, CUR, NXT) do {                                         \
    if ((kt_) + 1 < NSEQ / 64) STAGE_KV(NXT, (kt_) + 1);                      \
    f32x4 sacc[4];                                                            \
    _Pragma("unroll")                                                         \
    for (int mt = 0; mt < 4; ++mt) sacc[mt] = (f32x4){0.f, 0.f, 0.f, 0.f};    \
    __builtin_amdgcn_s_setprio(1);                                            \
    _Pragma("unroll")                                                         \
    for (int k = 0; k < 2; ++k) {                                             \
        _Pragma("unroll")                                                     \
        for (int mt = 0; mt < 4; ++mt) {                                      \
            bf16x8 ak = *(const bf16x8*)                                      \
                &Ks[CUR][(mt * 16 + l15) * 64 + ((quad * 8 + 32 * k) ^ swz)]; \
            sacc[mt] = __builtin_amdgcn_mfma_f32_16x16x32_bf16(               \
                ak, aq[k], sacc[mt], 0, 0, 0);                                \
        }                                                                     \
    }                                                                         \
    __builtin_amdgcn_s_setprio(0);                                            \
    _Pragma("unroll")                                                         \
    for (int mt = 0; mt < 4; ++mt) {                                          \
        f32x4 ev;                                                             \
        _Pragma("unroll")                                                     \
        for (int r = 0; r < 4; ++r) ev[r] = fexp2(sacc[mt][r]);               \
        bf16x4t pbk = __builtin_convertvector(ev, bf16x4t);                   \
        *(bf16x4t*)&Pw[l15 * 64 + ((mt * 16 + quad * 4) ^ swz)] = pbk;        \
    }                                                                         \
    __builtin_amdgcn_s_setprio(1);                                            \
    _Pragma("unroll")                                                         \
    for (int k = 0; k < 2; ++k) {                                             \
        bf16x8 ap = *(const bf16x8*)                                          \
            &Pw[l15 * 64 + ((quad * 8 + 32 * k) ^ swz)];                      \
        lacc = __builtin_amdgcn_mfma_f32_16x16x32_bf16(                       \
            ap, vone, lacc, 0, 0, 0);                                         \
        _Pragma("unroll")                                                     \
        for (int t = 0; t < 4; ++t) {                                         \
            bf16x8 bv = *(const bf16x8*)                                      \
                &Vs[CUR][(t * 16 + l15) * 64 + ((quad * 8 + 32 * k) ^ swz)];  \
            O[t] = __builtin_amdgcn_mfma_f32_16x16x32_bf16(                   \
                ap, bv, O[t], 0, 0, 0);                                       \
        }                                                                     \
    }                                                                         \
    __builtin_amdgcn_s_setprio(0);                                            \
    __syncthreads();                                                          \
} while (0)

__global__ __launch_bounds__(256)
void attn_kernel(const u16* __restrict__ Qb, const u16* __restrict__ Kb,
                 const u16* __restrict__ Vt, u16* __restrict__ AO)
{
    __shared__ __align__(16) u16 Ks[2][64 * 64];
    __shared__ __align__(16) u16 Vs[2][64 * 64];
    __shared__ __align__(16) u16 Ps[4][16 * 64];   // wave-private P tiles

    const int tid  = threadIdx.x;
    const int lane = tid & 63;
    const int wid  = tid >> 6;
    const int l15  = lane & 15;
    const int quad = lane >> 4;
    const int swz  = (l15 & 7) << 3;   // XOR swizzle for frag reads/P ops

    // XCD swizzle: xcd = f&7 -> bh in {3*xcd .. 3*xcd+2}; 96 blocks/XCD.
    const int f  = blockIdx.x;
    const int i  = f >> 3;
    const int bh = (f & 7) * 3 + (i >> 5);   // 0..23
    const int qt = i & 31;                   // 0..31

    const u16* Qg = Qb + ((size_t)bh * NSEQ + qt * 64) * HD;
    const u16* Kg = Kb + (size_t)bh * NSEQ * HD;
    const u16* Vg = Vt + (size_t)bh * HD * NSEQ;   // [64][2048]

    const int r0 = tid >> 3;
    const int cs = ((tid & 7) ^ (r0 & 7)) << 3;    // inverse-swizzled src col

    // Q fragments straight from global (rows are 128B; one-time read)
    bf16x8 aq[2];
    aq[0] = *(const bf16x8*)&Qg[(wid * 16 + l15) * HD + quad * 8];
    aq[1] = *(const bf16x8*)&Qg[(wid * 16 + l15) * HD + quad * 8 + 32];

    union { u16 s[8]; bf16x8 v; } oneu;
#pragma unroll
    for (int ii = 0; ii < 8; ++ii) oneu.s[ii] = 0x3f80;   // bf16 1.0
    const bf16x8 vone = oneu.v;

    f32x4 O[4];
#pragma unroll
    for (int t = 0; t < 4; ++t) O[t] = (f32x4){0.f, 0.f, 0.f, 0.f};
    f32x4 lacc = (f32x4){0.f, 0.f, 0.f, 0.f};   // softmax denominator rows

    u16* Pw = Ps[wid];

    STAGE_KV(0, 0);
    __syncthreads();

    for (int kt = 0; kt < NSEQ / 64; kt += 2) {
        ATTN_STEP(kt, 0, 1);
        ATTN_STEP(kt + 1, 1, 0);
    }

    float inv4[4];
#pragma unroll
    for (int r = 0; r < 4; ++r) inv4[r] = 1.0f / lacc[r];

    const int b = bh / NH, h = bh % NH;
#pragma unroll
    for (int r = 0; r < 4; ++r) {
        size_t orow = (size_t)b * NSEQ + qt * 64 + wid * 16 + quad * 4 + r;
#pragma unroll
        for (int t = 0; t < 4; ++t)
            AO[orow * CDIM + h * HD + t * 16 + l15] = f2bf(O[t][r] * inv4[r]);
    }
}

// ---------------------------------------------------------------------------
// Kernel 3: out = AO @ Wprojb^T + bias, bf16 MFMA (R13-proven, frozen).
// ---------------------------------------------------------------------------
#define PROJ_STAGE(BUF, kt_) do {                                             \
    _Pragma("unroll")                                                         \
    for (int it = 0; it < 2; ++it) {                                          \
        int ch = tid + 256 * it; int rr = ch >> 3;                            \
        int sc = ((ch & 7) ^ (rr & 7)) << 3;                                  \
        GLD16(Ag + (size_t)(m0 + rr) * CDIM + (kt_) + sc, &S[BUF][ch * 8]);   \
        GLD16(Wg + (size_t)(n0 + rr) * CDIM + (kt_) + sc,                     \
              &S[BUF][4096 + ch * 8]);                                        \
    }                                                                         \
} while (0)

__global__ __launch_bounds__(256)
void proj_kernel(const u16* __restrict__ Ag, const u16* __restrict__ Wg,
                 const float* __restrict__ bias, float* __restrict__ out)
{
    __shared__ __align__(16) u16 S[2][8192];   // [buf][A 64x64 | B 64x64]
    const int tid  = threadIdx.x;
    const int lane = tid & 63;
    const int wid  = tid >> 6;
    const int l15  = lane & 15;
    const int quad = lane >> 4;
    const int swz  = (l15 & 7) << 3;
    const int wr = wid >> 1, wc = wid & 1;

    // XCD-pinned m-slices (768 = 8 XCD x 8 m x 12 n), n-major within XCD
    const int f  = blockIdx.x;
    const int xc = f & 7;
    const int s  = f >> 3;                  // 0..95
    const int m0 = (xc * 8 + (s & 7)) * 64;
    const int n0 = (s >> 3) * 64;

    f32x4 acc[2][2];
#pragma unroll
    for (int mi = 0; mi < 2; ++mi)
#pragma unroll
        for (int ni = 0; ni < 2; ++ni)
            acc[mi][ni] = (f32x4){0.f, 0.f, 0.f, 0.f};

    PROJ_STAGE(0, 0);
    __syncthreads();

    int cur = 0;
    for (int kt = 0; kt < CDIM; kt += 64) {
        if (kt + 64 < CDIM) PROJ_STAGE(cur ^ 1, kt + 64);

#pragma unroll
        for (int k = 0; k < 2; ++k) {
            bf16x8 af[2], bf[2];
#pragma unroll
            for (int mi = 0; mi < 2; ++mi)
                af[mi] = *(const bf16x8*)
                    &S[cur][(wr * 32 + mi * 16 + l15) * 64
                            + ((quad * 8 + 32 * k) ^ swz)];
#pragma unroll
            for (int ni = 0; ni < 2; ++ni)
                bf[ni] = *(const bf16x8*)
                    &S[cur][4096 + (wc * 32 + ni * 16 + l15) * 64
                            + ((quad * 8 + 32 * k) ^ swz)];
#pragma unroll
            for (int mi = 0; mi < 2; ++mi)
#pragma unroll
                for (int ni = 0; ni < 2; ++ni)
                    acc[mi][ni] = __builtin_amdgcn_mfma_f32_16x16x32_bf16(
                        af[mi], bf[ni], acc[mi][ni], 0, 0, 0);
        }
        __syncthreads();
        cur ^= 1;
    }

#pragma unroll
    for (int ni = 0; ni < 2; ++ni) {
        int col = n0 + wc * 32 + ni * 16 + l15;
        float bb = bias[col];
#pragma unroll
        for (int mi = 0; mi < 2; ++mi) {
            int rw = m0 + wr * 32 + mi * 16 + quad * 4;
#pragma unroll
            for (int r = 0; r < 4; ++r)
                out[(size_t)(rw + r) * CDIM + col] = acc[mi][ni][r] + bb;
        }
    }
}

// ---------------------------------------------------------------------------
extern "C" void kernel_launch(void* const* d_in, const int* in_sizes, int n_in,
                              void* d_out, int out_size, void* d_ws,
                              size_t ws_size, hipStream_t stream)
{
    const float* X     = (const float*)d_in[0];   // [2, 2048, 768]
    const float* Wqkv  = (const float*)d_in[1];   // [2304, 768]
    const float* Wproj = (const float*)d_in[2];   // [768, 768]
    const float* bias  = (const float*)d_in[3];   // [768]
    float* out = (float*)d_out;                   // [2, 2048, 768]

    const size_t per_buf = (size_t)NB * NH * NSEQ * HD;   // 3145728
    u16* Qb  = (u16*)d_ws;
    u16* Kb  = Qb + per_buf;
    u16* Vb  = Kb + per_buf;                      // [B,H,64,N]
    u16* XAO = Vb + per_buf;      // Xb (conv->qkv), then AO (attn->proj)
    u16* Wqb = XAO + per_buf;                     // [2304,768] bf16
    u16* Wpb = Wqb + (size_t)3 * CDIM * CDIM;     // [768,768] bf16

    conv_kernel<<<dim3(2688), 256, 0, stream>>>(X, Wqkv, Wproj, XAO, Wqb, Wpb);
    qkv_mfma_kernel<<<dim3(1152), 256, 0, stream>>>(XAO, Wqb, Qb, Kb, Vb);
    attn_kernel<<<dim3(768), 256, 0, stream>>>(Qb, Kb, Vb, XAO);
    proj_kernel<<<dim3(768), 256, 0, stream>>>(XAO, Wpb, bias, out);
}